// Round 1
// baseline (425.439 us; speedup 1.0000x reference)
//
#include <hip/hip_runtime.h>

#define Nn    8192
#define FIN   256
#define FOUTc 128
#define MAXN  512   // degree ~ Binom(8192,0.01): mean 82, row max ~125 << 512

typedef float f32x4 __attribute__((ext_vector_type(4)));

// ---- Stage A: wps = W@phi_src, wpd = W@phi_dst. One wave per k; coalesced float2. ----
__global__ __launch_bounds__(256) void k_prep(const float* __restrict__ w,
                                              const float* __restrict__ phi,
                                              float* __restrict__ wps,
                                              float* __restrict__ wpd)
{
    const int k    = blockIdx.x * 4 + (threadIdx.x >> 6);   // 64 blocks x 4 waves = 256 k
    const int lane = threadIdx.x & 63;
    const float2 wv = ((const float2*)(w + (size_t)k * FOUTc))[lane];   // 512B/wave, coalesced
    const float2 ps = ((const float2*)phi)[lane];
    const float2 pd = ((const float2*)(phi + FOUTc))[lane];
    float a = wv.x * ps.x + wv.y * ps.y;
    float b = wv.x * pd.x + wv.y * pd.y;
#pragma unroll
    for (int off = 32; off > 0; off >>= 1) {
        a += __shfl_down(a, off, 64);
        b += __shfl_down(b, off, 64);
    }
    if (lane == 0) { wps[k] = a; wpd[k] = b; }
}

// ---- Stage B: s_src[i] = x[i]·wps ; s_dst[i] = x[i]·wpd (one wave per row) ----
__global__ __launch_bounds__(256) void k_s(const float* __restrict__ x,
                                           const float* __restrict__ wps,
                                           const float* __restrict__ wpd,
                                           float* __restrict__ s_src,
                                           float* __restrict__ s_dst)
{
    const int wid = threadIdx.x >> 6, lane = threadIdx.x & 63;
    const int row = blockIdx.x * 4 + wid;
    const float* xr = x + (size_t)row * FIN;
    float a = 0.f, b = 0.f;
#pragma unroll
    for (int q = 0; q < 4; q++) {
        const int k = lane + 64 * q;
        const float xv = xr[k];
        a = fmaf(xv, wps[k], a);
        b = fmaf(xv, wpd[k], b);
    }
#pragma unroll
    for (int off = 32; off > 0; off >>= 1) {
        a += __shfl_down(a, off, 64);
        b += __shfl_down(b, off, 64);
    }
    if (lane == 0) { s_src[row] = a; s_dst[row] = b; }
}

// ---- Stage C (512 threads/block): nt-prefetch adj row -> compaction (+pad to x8)
//      -> dense s_dst gather+max -> exact sparse softmax -> unnormalized
//      z = sum w_n x[j_n] split over 2 groups x 4 chains -> h = (z@W)*inv + bias.
//      exp(NEG_INF - m) == 0 in fp32 => sparse softmax exact; lrelu monotone =>
//      m = lrelu(s_src[i] + max_j s_dst[j]); self-loop guarantees l >= 1.
__global__ __launch_bounds__(512) void k_agg(const float* __restrict__ adj,
                                             const float* __restrict__ x,
                                             const float* __restrict__ w,
                                             const float* __restrict__ bias,
                                             const float* __restrict__ s_src,
                                             const float* __restrict__ s_dst,
                                             float* __restrict__ out)
{
    __shared__ int   nbr[MAXN];
    __shared__ float wts[MAXN];
    __shared__ float zs2[2][FIN];
    __shared__ float ph[4][FOUTc];
    __shared__ float red[8];
    __shared__ int   cnt;

    const int tid = threadIdx.x;
    const int i = blockIdx.x;
    if (tid == 0) cnt = 0;
    __syncthreads();

    // Phase 1a: nontemporal prefetch of the full 32KB row (4 x float4 per thread).
    // adj is single-use streaming data: nt keeps it from evicting x/W in L2.
    const f32x4* arow4 = (const f32x4*)(adj + (size_t)i * Nn);
    f32x4 buf[4];
#pragma unroll
    for (int t = 0; t < 4; t++) buf[t] = __builtin_nontemporal_load(arow4 + t * 512 + tid);

    // Phase 1b: compact nonzero columns (+ self-loop). Branch body is index-store only.
#pragma unroll
    for (int t = 0; t < 4; t++) {
        const int j0 = (t * 512 + tid) * 4;
#pragma unroll
        for (int p = 0; p < 4; p++) {
            const int j = j0 + p;
            if (buf[t][p] != 0.f || j == i) {          // mask = adj + I > 0
                const int pos = atomicAdd(&cnt, 1);
                if (pos < MAXN) nbr[pos] = j;
            }
        }
    }
    __syncthreads();
    const int L    = (cnt < MAXN) ? cnt : MAXN;
    const int Lpad = (L + 7) & ~7;                     // pad list to x8 for clean unroll
    if (tid < Lpad - L) nbr[L + tid] = i;              // disjoint slots; visible after later syncs

    // Phase 1c: dense parallel s_dst gather + block max.
    float lmax = -1e30f;
    for (int n = tid; n < L; n += 512) {
        const float sd = s_dst[nbr[n]];
        wts[n] = sd;
        lmax = fmaxf(lmax, sd);
    }
#pragma unroll
    for (int off = 32; off > 0; off >>= 1) lmax = fmaxf(lmax, __shfl_down(lmax, off, 64));
    if ((tid & 63) == 0) red[tid >> 6] = lmax;
    __syncthreads();
    float maxd = red[0];
#pragma unroll
    for (int r = 1; r < 8; r++) maxd = fmaxf(maxd, red[r]);
    const float ssi = s_src[i];
    const float Sm  = ssi + maxd;
    const float m_i = (Sm >= 0.f) ? Sm : 0.2f * Sm;

    // Phase 2: softmax weights + denominator (unnormalized; 1/l applied in epilogue).
    float lsum = 0.f;
    for (int n = tid; n < L; n += 512) {
        float S = ssi + wts[n];
        S = (S >= 0.f) ? S : 0.2f * S;
        const float wv = __expf(S - m_i);
        wts[n] = wv;
        lsum += wv;
    }
    if (tid < Lpad - L) wts[L + tid] = 0.f;            // padded entries contribute nothing
#pragma unroll
    for (int off = 32; off > 0; off >>= 1) lsum += __shfl_down(lsum, off, 64);
    __syncthreads();                       // red(max) consumed by all threads
    if ((tid & 63) == 0) red[tid >> 6] = lsum;
    __syncthreads();                       // publishes wts[], nbr padding, red(sum)
    float l_i = red[0];
#pragma unroll
    for (int r = 1; r < 8; r++) l_i += red[r];
    const float inv = 1.f / l_i;

    // Phase 3: unnormalized z[c] = sum_n w_n * x[j_n][c].
    // 2 groups split the neighbor list; 4 independent chains -> 4 gathers in flight.
    const int c = tid & 255;               // feature
    const int g = tid >> 8;                // neighbor-list half
    const int Lh = Lpad >> 1;              // multiple of 4
    const int base = g * Lh;
    const float* xc = x + c;
    float z0 = 0.f, z1 = 0.f, z2 = 0.f, z3 = 0.f;
    for (int n = base; n < base + Lh; n += 4) {
        const int j0 = nbr[n], j1 = nbr[n+1], j2 = nbr[n+2], j3 = nbr[n+3];
        const float w0 = wts[n], w1 = wts[n+1], w2 = wts[n+2], w3 = wts[n+3];
        z0 = fmaf(w0, xc[(size_t)j0 * FIN], z0);
        z1 = fmaf(w1, xc[(size_t)j1 * FIN], z1);
        z2 = fmaf(w2, xc[(size_t)j2 * FIN], z2);
        z3 = fmaf(w3, xc[(size_t)j3 * FIN], z3);
    }
    zs2[g][c] = (z0 + z1) + (z2 + z3);
    __syncthreads();

    // Phase 4: h[o] = inv * sum_k z[k] * W[k][o]; 4 quarters of k per output o.
    const int o = tid & 127, q = tid >> 7;
    const float* wcol = w + (size_t)(q * 64) * FOUTc + o;
    float acc = 0.f;
#pragma unroll 8
    for (int k = 0; k < 64; k++) {
        const float zsum = zs2[0][q * 64 + k] + zs2[1][q * 64 + k];
        acc = fmaf(zsum, wcol[(size_t)k * FOUTc], acc);
    }
    ph[q][o] = acc;
    __syncthreads();
    if (tid < FOUTc)
        out[(size_t)i * FOUTc + tid] =
            (ph[0][tid] + ph[1][tid] + ph[2][tid] + ph[3][tid]) * inv + bias[tid];
}

extern "C" void kernel_launch(void* const* d_in, const int* in_sizes, int n_in,
                              void* d_out, int out_size, void* d_ws, size_t ws_size,
                              hipStream_t stream)
{
    (void)out_size; (void)ws_size;
    const float* adj  = (const float*)d_in[0];
    const float* x    = (const float*)d_in[1];
    const float* w    = (const float*)d_in[2];
    const float* bias = (const float*)d_in[3];
    const float* phi  = (const float*)d_in[4];
    for (int i = 0; i < n_in; i++) {
        switch (in_sizes[i]) {
            case Nn * Nn:     adj  = (const float*)d_in[i]; break;
            case Nn * FIN:    x    = (const float*)d_in[i]; break;
            case FIN * FOUTc: w    = (const float*)d_in[i]; break;
            case FOUTc:       bias = (const float*)d_in[i]; break;
            case 2 * FOUTc:   phi  = (const float*)d_in[i]; break;
        }
    }
    float* out = (float*)d_out;

    float* wps   = (float*)d_ws;
    float* wpd   = wps + FIN;
    float* s_src = wpd + FIN;
    float* s_dst = s_src + Nn;

    hipLaunchKernelGGL(k_prep, dim3(64),   dim3(256), 0, stream, w, phi, wps, wpd);
    hipLaunchKernelGGL(k_s,    dim3(Nn/4), dim3(256), 0, stream, x, wps, wpd, s_src, s_dst);
    hipLaunchKernelGGL(k_agg,  dim3(Nn),   dim3(512), 0, stream,
                       adj, x, w, bias, s_src, s_dst, out);
}

// Round 2
// 409.065 us; speedup vs baseline: 1.0400x; 1.0400x over previous
//
#include <hip/hip_runtime.h>

#define Nn    8192
#define FIN   256
#define FOUTc 128
#define MAXN  512   // degree ~ Binom(8192,0.01): mean 82, row max ~125 << 512

typedef float f32x4 __attribute__((ext_vector_type(4)));

// ---- Stage 1: x' = x@W + bias (materialized, 4 MB -> L2-resident), fused with
//      s_src = x'·phi_src, s_dst = x'·phi_dst. One wave per 4 rows: W read as
//      float2/lane (coalesced, L2-hot, reused 4x), x via wave-uniform loads. ----
__global__ __launch_bounds__(256) void k_xp(const float* __restrict__ x,
                                            const float* __restrict__ w,
                                            const float* __restrict__ bias,
                                            const float* __restrict__ phi,
                                            float* __restrict__ xp,
                                            float* __restrict__ s_src,
                                            float* __restrict__ s_dst)
{
    const int wave = blockIdx.x * 4 + (threadIdx.x >> 6);   // 512 blocks x 4 waves = 2048
    const int lane = threadIdx.x & 63;
    const int row0 = wave * 4;

    const float2 bv = ((const float2*)bias)[lane];
    const float2 ps = ((const float2*)phi)[lane];
    const float2 pd = ((const float2*)(phi + FOUTc))[lane];

    const float* xr = x + (size_t)row0 * FIN;
    float2 acc[4];
#pragma unroll
    for (int r = 0; r < 4; r++) acc[r] = make_float2(0.f, 0.f);

#pragma unroll 4
    for (int k = 0; k < FIN; k++) {
        const float2 wv = ((const float2*)(w + (size_t)k * FOUTc))[lane];
        const float xv0 = xr[k];
        const float xv1 = xr[FIN + k];
        const float xv2 = xr[2 * FIN + k];
        const float xv3 = xr[3 * FIN + k];
        acc[0].x = fmaf(xv0, wv.x, acc[0].x); acc[0].y = fmaf(xv0, wv.y, acc[0].y);
        acc[1].x = fmaf(xv1, wv.x, acc[1].x); acc[1].y = fmaf(xv1, wv.y, acc[1].y);
        acc[2].x = fmaf(xv2, wv.x, acc[2].x); acc[2].y = fmaf(xv2, wv.y, acc[2].y);
        acc[3].x = fmaf(xv3, wv.x, acc[3].x); acc[3].y = fmaf(xv3, wv.y, acc[3].y);
    }

#pragma unroll
    for (int r = 0; r < 4; r++) {
        const float2 h = make_float2(acc[r].x + bv.x, acc[r].y + bv.y);
        ((float2*)(xp + (size_t)(row0 + r) * FOUTc))[lane] = h;
        float a = h.x * ps.x + h.y * ps.y;
        float b = h.x * pd.x + h.y * pd.y;
#pragma unroll
        for (int off = 32; off > 0; off >>= 1) {
            a += __shfl_down(a, off, 64);
            b += __shfl_down(b, off, 64);
        }
        if (lane == 0) { s_src[row0 + r] = a; s_dst[row0 + r] = b; }
    }
}

// ---- Stage 2 (512 threads/block): nt-prefetch adj row -> compaction (+pad to x8)
//      -> dense s_dst gather+max -> exact sparse softmax -> h[i][o] = inv * sum_n
//      w_n * x'[j_n][o] directly in output space (4 groups x 128 features).
//      exp(NEG_INF - m) == 0 in fp32 => sparse softmax exact; lrelu monotone =>
//      m = lrelu(s_src[i] + max_j s_dst[j]); self-loop guarantees l >= 1.
//      bias is folded into x' (softmax weights sum to 1). ----
__global__ __launch_bounds__(512) void k_agg(const float* __restrict__ adj,
                                             const float* __restrict__ xp,
                                             const float* __restrict__ s_src,
                                             const float* __restrict__ s_dst,
                                             float* __restrict__ out)
{
    __shared__ int   nbr[MAXN];
    __shared__ float wts[MAXN];
    __shared__ float hp[4][FOUTc];
    __shared__ float red[8];
    __shared__ int   cnt;

    const int tid = threadIdx.x;
    const int i = blockIdx.x;
    if (tid == 0) cnt = 0;
    __syncthreads();

    // Phase 1a: nontemporal prefetch of the full 32KB row (4 x float4 per thread).
    // adj is single-use streaming data: nt keeps it from evicting xp in L2.
    const f32x4* arow4 = (const f32x4*)(adj + (size_t)i * Nn);
    f32x4 buf[4];
#pragma unroll
    for (int t = 0; t < 4; t++) buf[t] = __builtin_nontemporal_load(arow4 + t * 512 + tid);

    // Phase 1b: compact nonzero columns (+ self-loop). Branch body is index-store only.
#pragma unroll
    for (int t = 0; t < 4; t++) {
        const int j0 = (t * 512 + tid) * 4;
#pragma unroll
        for (int p = 0; p < 4; p++) {
            const int j = j0 + p;
            if (buf[t][p] != 0.f || j == i) {          // mask = adj + I > 0
                const int pos = atomicAdd(&cnt, 1);
                if (pos < MAXN) nbr[pos] = j;
            }
        }
    }
    __syncthreads();
    const int L    = (cnt < MAXN) ? cnt : MAXN;
    const int Lpad = (L + 7) & ~7;                     // pad list to x8: quarters stay x2
    if (tid < Lpad - L) nbr[L + tid] = i;              // disjoint slots; visible after syncs

    // Phase 1c: dense parallel s_dst gather + block max.
    float lmax = -1e30f;
    for (int n = tid; n < L; n += 512) {
        const float sd = s_dst[nbr[n]];
        wts[n] = sd;
        lmax = fmaxf(lmax, sd);
    }
#pragma unroll
    for (int off = 32; off > 0; off >>= 1) lmax = fmaxf(lmax, __shfl_down(lmax, off, 64));
    if ((tid & 63) == 0) red[tid >> 6] = lmax;
    __syncthreads();
    float maxd = red[0];
#pragma unroll
    for (int r = 1; r < 8; r++) maxd = fmaxf(maxd, red[r]);
    const float ssi = s_src[i];
    const float Sm  = ssi + maxd;
    const float m_i = (Sm >= 0.f) ? Sm : 0.2f * Sm;

    // Phase 2: softmax weights + denominator (unnormalized; 1/l applied in epilogue).
    float lsum = 0.f;
    for (int n = tid; n < L; n += 512) {
        float S = ssi + wts[n];
        S = (S >= 0.f) ? S : 0.2f * S;
        const float wv = __expf(S - m_i);
        wts[n] = wv;
        lsum += wv;
    }
    if (tid < Lpad - L) wts[L + tid] = 0.f;            // padded entries contribute nothing
#pragma unroll
    for (int off = 32; off > 0; off >>= 1) lsum += __shfl_down(lsum, off, 64);
    __syncthreads();                       // red(max) consumed by all threads
    if ((tid & 63) == 0) red[tid >> 6] = lsum;
    __syncthreads();                       // publishes wts[], nbr padding, red(sum)
    float l_i = red[0];
#pragma unroll
    for (int r = 1; r < 8; r++) l_i += red[r];
    const float inv = 1.f / l_i;

    // Phase 3: h[o] = sum_n w_n * x'[j_n][o]. 4 groups split the neighbor list;
    // 2 independent chains each; per-neighbor load is 512B coalesced from L2 (xp = 4MB).
    const int o  = tid & 127;
    const int g  = tid >> 7;
    const int Lq = Lpad >> 2;              // multiple of 2
    const int base = g * Lq;
    const float* xpo = xp + o;
    float h0 = 0.f, h1 = 0.f;
    for (int n = base; n < base + Lq; n += 2) {
        const int   j0 = nbr[n],   j1 = nbr[n + 1];
        const float w0 = wts[n],   w1 = wts[n + 1];
        h0 = fmaf(w0, xpo[(size_t)j0 * FOUTc], h0);
        h1 = fmaf(w1, xpo[(size_t)j1 * FOUTc], h1);
    }
    hp[g][o] = h0 + h1;
    __syncthreads();
    if (tid < FOUTc)
        out[(size_t)i * FOUTc + tid] =
            ((hp[0][tid] + hp[1][tid]) + (hp[2][tid] + hp[3][tid])) * inv;  // bias in x'
}

extern "C" void kernel_launch(void* const* d_in, const int* in_sizes, int n_in,
                              void* d_out, int out_size, void* d_ws, size_t ws_size,
                              hipStream_t stream)
{
    (void)out_size; (void)ws_size;
    const float* adj  = (const float*)d_in[0];
    const float* x    = (const float*)d_in[1];
    const float* w    = (const float*)d_in[2];
    const float* bias = (const float*)d_in[3];
    const float* phi  = (const float*)d_in[4];
    for (int i = 0; i < n_in; i++) {
        switch (in_sizes[i]) {
            case Nn * Nn:     adj  = (const float*)d_in[i]; break;
            case Nn * FIN:    x    = (const float*)d_in[i]; break;
            case FIN * FOUTc: w    = (const float*)d_in[i]; break;
            case FOUTc:       bias = (const float*)d_in[i]; break;
            case 2 * FOUTc:   phi  = (const float*)d_in[i]; break;
        }
    }
    float* out = (float*)d_out;

    float* xp    = (float*)d_ws;             // 8192 x 128 = 4 MB
    float* s_src = xp + (size_t)Nn * FOUTc;  // 32 KB
    float* s_dst = s_src + Nn;               // 32 KB

    hipLaunchKernelGGL(k_xp,  dim3(512), dim3(256), 0, stream,
                       x, w, bias, phi, xp, s_src, s_dst);
    hipLaunchKernelGGL(k_agg, dim3(Nn),  dim3(512), 0, stream,
                       adj, xp, s_src, s_dst, out);
}